// Round 13
// baseline (331.112 us; speedup 1.0000x reference)
//
#include <hip/hip_runtime.h>
#include <hip/hip_bf16.h>
#include <stdint.h>

// Problem constants
#define DMODEL 1024
#define NHEADS 16
#define DK 64
#define TQ 64      // chunk_len
#define LKV 256    // kv length per chunk (NN*NL)
#define MQ 8192    // B*S = query rows
#define MKV 32768  // B*NC*L = kv rows

typedef __bf16 bf16x8 __attribute__((ext_vector_type(8)));
typedef float f32x4 __attribute__((ext_vector_type(4)));
typedef unsigned short u16x8 __attribute__((ext_vector_type(8)));
typedef unsigned short u16;

__device__ __forceinline__ unsigned short f2bf(float f) {
    union { float f; unsigned int i; } x; x.f = f;
    unsigned int r = (x.i + 0x7FFFu + ((x.i >> 16) & 1u)) >> 16;
    return (unsigned short)r;
}

__device__ __forceinline__ void gload_lds16(const void* g, void* l) {
    __builtin_amdgcn_global_load_lds(
        (const __attribute__((address_space(1))) unsigned int*)g,
        (__attribute__((address_space(3))) unsigned int*)l, 16, 0, 0);
}

// ---------------- f32 -> bf16 convert (8 elems/thread) ----------------
__global__ __launch_bounds__(256) void cvt_f32_bf16(const float* __restrict__ in,
                                                    unsigned short* __restrict__ out) {
    long long i = ((long long)blockIdx.x * 256 + threadIdx.x) * 8;
    f32x4 a = *(const f32x4*)(in + i);
    f32x4 b = *(const f32x4*)(in + i + 4);
    u16x8 o;
    o[0] = f2bf(a[0]); o[1] = f2bf(a[1]); o[2] = f2bf(a[2]); o[3] = f2bf(a[3]);
    o[4] = f2bf(b[0]); o[5] = f2bf(b[1]); o[6] = f2bf(b[2]); o[7] = f2bf(b[3]);
    *(u16x8*)(out + i) = o;
}

// ---------------- fused weight transpose+convert: Wt[n][k] = bf16(W[k][n]) ----------------
__global__ __launch_bounds__(256) void transpose_w_cvt4(const float* __restrict__ w0,
                                                        const float* __restrict__ w1,
                                                        const float* __restrict__ w2,
                                                        const float* __restrict__ w3,
                                                        u16* __restrict__ o0,
                                                        u16* __restrict__ o1,
                                                        u16* __restrict__ o2,
                                                        u16* __restrict__ o3) {
    __shared__ float tile[64][65];
    const float* in; u16* out;
    switch (blockIdx.z) {
        case 0: in = w0; out = o0; break;
        case 1: in = w1; out = o1; break;
        case 2: in = w2; out = o2; break;
        default: in = w3; out = o3; break;
    }
    int bi = blockIdx.y, bj = blockIdx.x;
    int tid = threadIdx.x;
    int c = tid & 63, r0 = tid >> 6;
#pragma unroll
    for (int p = 0; p < 16; ++p) {
        int r = r0 + 4 * p;
        tile[r][c] = in[(size_t)(bi * 64 + r) * 1024 + bj * 64 + c];
    }
    __syncthreads();
#pragma unroll
    for (int p = 0; p < 16; ++p) {
        int r = r0 + 4 * p;
        out[(size_t)(bj * 64 + r) * 1024 + bi * 64 + c] = f2bf(tile[c][r]);
    }
}

// ---------------- 128x128 GEMM (proven) for the O projection ----------------
template <int OUTMODE>
__global__ __launch_bounds__(256) void gemm_bias(const u16* __restrict__ A,
                                                 const u16* __restrict__ Bt,
                                                 const float* __restrict__ bias,
                                                 void* __restrict__ OutV) {
    __shared__ alignas(16) u16 aLds[128 * 32];
    __shared__ alignas(16) u16 bLds[128 * 32];

    int tid = threadIdx.x;
    int lane = tid & 63, wid = tid >> 6;
    int m0 = blockIdx.x * 128;
    int n0 = blockIdx.y * 128;
    int wr = (wid >> 1) * 64, wc = (wid & 1) * 64;

    f32x4 zero = {0.f, 0.f, 0.f, 0.f};
    f32x4 acc[4][4];
#pragma unroll
    for (int i = 0; i < 4; ++i)
#pragma unroll
        for (int j = 0; j < 4; ++j) acc[i][j] = zero;

    int sr = lane >> 2;
    int sk = (lane & 3) * 8;
    const u16* aG = A + (size_t)(m0 + sr) * 1024 + sk;
    const u16* bG = Bt + (size_t)(n0 + sr) * 1024 + sk;
    int c0 = wid, c1 = wid + 4;

    int fr = lane & 15, fg = (lane >> 4) * 8;

    for (int kt = 0; kt < 1024; kt += 32) {
        gload_lds16(aG + (size_t)(c0 * 16) * 1024 + kt, aLds + c0 * 512);
        gload_lds16(aG + (size_t)(c1 * 16) * 1024 + kt, aLds + c1 * 512);
        gload_lds16(bG + (size_t)(c0 * 16) * 1024 + kt, bLds + c0 * 512);
        gload_lds16(bG + (size_t)(c1 * 16) * 1024 + kt, bLds + c1 * 512);
        __syncthreads();

        bf16x8 af[4], bf[4];
#pragma unroll
        for (int mt = 0; mt < 4; ++mt)
            af[mt] = *(const bf16x8*)&aLds[(wr + mt * 16 + fr) * 32 + fg];
#pragma unroll
        for (int nt = 0; nt < 4; ++nt)
            bf[nt] = *(const bf16x8*)&bLds[(wc + nt * 16 + fr) * 32 + fg];
#pragma unroll
        for (int mt = 0; mt < 4; ++mt)
#pragma unroll
            for (int nt = 0; nt < 4; ++nt)
                acc[mt][nt] = __builtin_amdgcn_mfma_f32_16x16x32_bf16(af[mt], bf[nt], acc[mt][nt], 0, 0, 0);
        __syncthreads();
    }

    float bv[4];
#pragma unroll
    for (int nt = 0; nt < 4; ++nt) bv[nt] = bias[n0 + wc + nt * 16 + fr];

    if (OUTMODE == 0) {
        u16* Out = (u16*)OutV;
#pragma unroll
        for (int mt = 0; mt < 4; ++mt)
#pragma unroll
            for (int r = 0; r < 4; ++r) {
                size_t row = (size_t)(m0 + wr + mt * 16 + (lane >> 4) * 4 + r);
#pragma unroll
                for (int nt = 0; nt < 4; ++nt)
                    Out[row * 1024 + n0 + wc + nt * 16 + fr] = f2bf(acc[mt][nt][r] + bv[nt]);
            }
    } else {
        float* Out = (float*)OutV;
#pragma unroll
        for (int mt = 0; mt < 4; ++mt)
#pragma unroll
            for (int r = 0; r < 4; ++r) {
                size_t row = (size_t)(m0 + wr + mt * 16 + (lane >> 4) * 4 + r);
#pragma unroll
                for (int nt = 0; nt < 4; ++nt)
                    Out[row * 1024 + n0 + wc + nt * 16 + fr] = acc[mt][nt][r] + bv[nt];
            }
    }
}

// ================= fused Q/K/V projection: 128x256, BK=32, 2 blocks/CU =================
// Mechanism: 48 KB LDS + <=128 VGPR -> 2 blocks/CU (4 waves/SIMD). Cross-block
// overlap hides all per-tile sync (m114): while one block drains vmcnt/barrier,
// the other issues MFMA.  r10 minimal-sync anatomy: per tile {8 ds_read_b128 ->
// 3 stage calls (t+1) -> 16 MFMA -> vmcnt(0)+barrier}.  LDS slot swizzle:
// content(row, s) comes from source slot s ^ ((row>>1)&3) -> column b128 reads
// touch each 16B slot exactly once (conflict-free).

// Stage 128 rows x 32 cols (8 KB) from src (pre-offset to row0*1024 + t*32).
__device__ __forceinline__ void stage128(const u16* src, u16* ldsDst, int tid) {
    int l = tid & 63;
    int row = tid >> 2;
    int slot = (l & 3) ^ ((l >> 3) & 3);
    gload_lds16(src + (size_t)row * 1024 + slot * 8, ldsDst + (size_t)(tid >> 6) * 512);
}

#define SBAR() do { __builtin_amdgcn_s_barrier(); asm volatile("" ::: "memory"); } while (0)

__global__ __launch_bounds__(512, 4) void proj_fused(const u16* __restrict__ Akv,
                                                     const u16* __restrict__ Aq,
                                                     const u16* __restrict__ WkT,
                                                     const u16* __restrict__ WvT,
                                                     const u16* __restrict__ WqT,
                                                     const float* __restrict__ bk,
                                                     const float* __restrict__ bv,
                                                     const float* __restrict__ bq,
                                                     u16* __restrict__ Kp,
                                                     u16* __restrict__ Vt,
                                                     u16* __restrict__ Qp,
                                                     int nmKV, int nmQ) {
    __shared__ alignas(16) u16 lds[24576];   // 48 KB: A0(8K) A1(8K) B0(16K) B1(16K)
    u16* ldsA0 = lds;          u16* ldsA1 = lds + 4096;
    u16* ldsB0 = lds + 8192;   u16* ldsB1 = lds + 16384;

    int tid = threadIdx.x, lane = tid & 63, wid = tid >> 6;
    int wm = wid >> 2, wn = wid & 3;       // 2M x 4N waves, wave tile 64x64
    int fr = lane & 15, g = lane >> 4;

    // bijective XCD swizzle
    int nB = gridDim.x;
    int bid = blockIdx.x;
    int qq = nB >> 3, rr = nB & 7;
    int xcd = bid & 7, idx = bid >> 3;
    int wg = (xcd < rr) ? xcd * (qq + 1) + idx : rr * (qq + 1) + (xcd - rr) * qq + idx;

    // decode role
    const u16* A; const u16* B; const float* bias; u16* Out; int mode;
    int nKV4 = nmKV * 4;
    int lwg;
    if (wg < nKV4)            { lwg = wg;            A = Akv; B = WkT; bias = bk; Out = Kp; mode = 0; }
    else if (wg < 2 * nKV4)   { lwg = wg - nKV4;     A = Akv; B = WvT; bias = bv; Out = Vt; mode = 1; }
    else                      { lwg = wg - 2 * nKV4; A = Aq;  B = WqT; bias = bq; Out = Qp; mode = 0; }
    int m0 = (lwg >> 2) * 128;
    int n0 = (lwg & 3) * 256;

    const u16* aSrc = A + (size_t)m0 * 1024;
    const u16* bSrc = B + (size_t)n0 * 1024;
    const u16* bSrc2 = bSrc + (size_t)128 * 1024;

    f32x4 zero = {0.f, 0.f, 0.f, 0.f};
    f32x4 acc[4][4];
#pragma unroll
    for (int i = 0; i < 4; ++i)
#pragma unroll
        for (int j = 0; j < 4; ++j) acc[i][j] = zero;

    bf16x8 aF[4], bF[4];

#define LADDR(row) ((row) * 32 + (((g ^ (((row) >> 1) & 3))) << 3))
#define READ_AB(lA, lB)                                                          \
    do {                                                                         \
        _Pragma("unroll") for (int mf = 0; mf < 4; ++mf) {                       \
            int row = wm * 64 + mf * 16 + fr;                                    \
            aF[mf] = *(const bf16x8*)&(lA)[LADDR(row)];                          \
        }                                                                        \
        _Pragma("unroll") for (int nf = 0; nf < 4; ++nf) {                       \
            int row = wn * 64 + nf * 16 + fr;                                    \
            bF[nf] = *(const bf16x8*)&(lB)[LADDR(row)];                          \
        }                                                                        \
    } while (0)
#define MFMA16()                                                                 \
    do {                                                                         \
        __builtin_amdgcn_s_setprio(1);                                           \
        _Pragma("unroll") for (int mf = 0; mf < 4; ++mf)                         \
            _Pragma("unroll") for (int nf = 0; nf < 4; ++nf)                     \
                acc[mf][nf] = __builtin_amdgcn_mfma_f32_16x16x32_bf16(           \
                    aF[mf], bF[nf], acc[mf][nf], 0, 0, 0);                       \
        __builtin_amdgcn_s_setprio(0);                                           \
    } while (0)

    // ---- prologue: stage tile 0 into buf0 ----
    stage128(aSrc, ldsA0, tid);
    stage128(bSrc, ldsB0, tid);
    stage128(bSrc2, ldsB0 + 4096, tid);
    asm volatile("s_waitcnt vmcnt(0)" ::: "memory");
    SBAR();

    for (int t = 0; t < 32; ++t) {
        u16* lA = (t & 1) ? ldsA1 : ldsA0;
        u16* lB = (t & 1) ? ldsB1 : ldsB0;
        u16* pA = (t & 1) ? ldsA0 : ldsA1;
        u16* pB = (t & 1) ? ldsB0 : ldsB1;
        bool pf = (t < 31);

        READ_AB(lA, lB);
        if (pf) {
            stage128(aSrc + (t + 1) * 32, pA, tid);
            stage128(bSrc + (t + 1) * 32, pB, tid);
            stage128(bSrc2 + (t + 1) * 32, pB + 4096, tid);
        }
        MFMA16();
        asm volatile("s_waitcnt vmcnt(0)" ::: "memory");
        SBAR();
    }

    // ---- epilogue ----
    float bvv[4];
#pragma unroll
    for (int NF = 0; NF < 4; ++NF) bvv[NF] = bias[n0 + wn * 64 + NF * 16 + fr];

    if (mode == 0) {
#pragma unroll
        for (int MF = 0; MF < 4; ++MF)
#pragma unroll
            for (int r = 0; r < 4; ++r) {
                size_t row = (size_t)(m0 + wm * 64 + MF * 16 + (lane >> 4) * 4 + r);
#pragma unroll
                for (int NF = 0; NF < 4; ++NF)
                    Out[row * 1024 + n0 + wn * 64 + NF * 16 + fr] =
                        f2bf(acc[MF][NF][r] + bvv[NF]);
            }
    } else {
        // Vt[((bcL*16 + h)*64 + d) * 256 + lv]
#pragma unroll
        for (int MF = 0; MF < 4; ++MF)
#pragma unroll
            for (int r = 0; r < 4; ++r) {
                int gm = m0 + wm * 64 + MF * 16 + (lane >> 4) * 4 + r;
                int bc2 = gm >> 8, lv = gm & 255;
#pragma unroll
                for (int NF = 0; NF < 4; ++NF) {
                    int n = n0 + wn * 64 + NF * 16 + fr;
                    int hh = n >> 6, dd = n & 63;
                    Out[(size_t)((bc2 * 16 + hh) * 64 + dd) * 256 + lv] =
                        f2bf(acc[MF][NF][r] + bvv[NF]);
                }
            }
    }
#undef LADDR
#undef READ_AB
#undef MFMA16
}

// ---------------- attention: per (bcLocal, h) block ----------------
// Chunked XCD swizzle: all 16 head-blocks of one bc land on the same XCD
// so K[bc]/V[bc] are fetched into that XCD's L2 once, not 8x.
__global__ __launch_bounds__(256) void attn_kernel(const u16* __restrict__ Q,
                                                   const u16* __restrict__ K,
                                                   const u16* __restrict__ Vt,
                                                   u16* O) {
    __shared__ alignas(16) u16 pLds[64 * 264];

    int tid = threadIdx.x;
    int lane = tid & 63, w = tid >> 6;
    int nBl = gridDim.x;
    int wk = (blockIdx.x & 7) * (nBl >> 3) + (blockIdx.x >> 3);  // chunked (nBl%8==0)
    int bc = wk >> 4, h = wk & 15;
    int fr = lane & 15, g = lane >> 4;

    const u16* qb = Q + (size_t)(bc * 64 + w * 16 + fr) * 1024 + h * 64 + g * 8;
    bf16x8 qf0 = *(const bf16x8*)qb;
    bf16x8 qf1 = *(const bf16x8*)(qb + 32);

    const u16* kb = K + (size_t)(bc * 256 + fr) * 1024 + h * 64 + g * 8;

    f32x4 zero = {0.f, 0.f, 0.f, 0.f};
    f32x4 sc[16];
#pragma unroll
    for (int nt = 0; nt < 16; ++nt) sc[nt] = zero;

#pragma unroll
    for (int nt = 0; nt < 16; ++nt) {
        bf16x8 kf0 = *(const bf16x8*)(kb + (size_t)(nt * 16) * 1024);
        bf16x8 kf1 = *(const bf16x8*)(kb + (size_t)(nt * 16) * 1024 + 32);
        sc[nt] = __builtin_amdgcn_mfma_f32_16x16x32_bf16(qf0, kf0, sc[nt], 0, 0, 0);
        sc[nt] = __builtin_amdgcn_mfma_f32_16x16x32_bf16(qf1, kf1, sc[nt], 0, 0, 0);
    }

    const float scale = 0.125f;
    float mx[4], sum[4];
#pragma unroll
    for (int r = 0; r < 4; ++r) {
        float m = -1e30f;
#pragma unroll
        for (int nt = 0; nt < 16; ++nt) {
            sc[nt][r] *= scale;
            m = fmaxf(m, sc[nt][r]);
        }
#pragma unroll
        for (int x = 1; x < 16; x <<= 1) m = fmaxf(m, __shfl_xor(m, x, 64));
        mx[r] = m;
        sum[r] = 0.f;
    }
#pragma unroll
    for (int nt = 0; nt < 16; ++nt)
#pragma unroll
        for (int r = 0; r < 4; ++r) {
            float p = __expf(sc[nt][r] - mx[r]);
            sum[r] += p;
            pLds[(w * 16 + g * 4 + r) * 264 + nt * 16 + fr] = f2bf(p);
        }
#pragma unroll
    for (int r = 0; r < 4; ++r)
#pragma unroll
        for (int x = 1; x < 16; x <<= 1) sum[r] += __shfl_xor(sum[r], x, 64);

    __syncthreads();

    f32x4 oa[4];
#pragma unroll
    for (int nt = 0; nt < 4; ++nt) oa[nt] = zero;

    const u16* vtb = Vt + (size_t)((bc * 16 + h) * 64) * 256;
#pragma unroll
    for (int ks = 0; ks < 8; ++ks) {
        bf16x8 pf = *(const bf16x8*)&pLds[(w * 16 + fr) * 264 + ks * 32 + g * 8];
#pragma unroll
        for (int nt = 0; nt < 4; ++nt) {
            bf16x8 vf = *(const bf16x8*)(vtb + (size_t)(nt * 16 + fr) * 256 + ks * 32 + g * 8);
            oa[nt] = __builtin_amdgcn_mfma_f32_16x16x32_bf16(pf, vf, oa[nt], 0, 0, 0);
        }
    }

    float rs[4];
#pragma unroll
    for (int r = 0; r < 4; ++r) rs[r] = 1.0f / sum[r];

    u16* ob = O + (size_t)(bc * 64 + w * 16 + g * 4) * 1024 + h * 64 + fr;
#pragma unroll
    for (int nt = 0; nt < 4; ++nt)
#pragma unroll
        for (int r = 0; r < 4; ++r)
            ob[(size_t)r * 1024 + nt * 16] = f2bf(oa[nt][r] * rs[r]);
}

extern "C" void kernel_launch(void* const* d_in, const int* in_sizes, int n_in,
                              void* d_out, int out_size, void* d_ws, size_t ws_size,
                              hipStream_t stream) {
    const float* query = (const float*)d_in[0];
    const float* keyin = (const float*)d_in[1];
    const float* Wq = (const float*)d_in[2];
    const float* bq = (const float*)d_in[3];
    const float* Wk = (const float*)d_in[4];
    const float* bk = (const float*)d_in[5];
    const float* Wv = (const float*)d_in[6];
    const float* bv = (const float*)d_in[7];
    const float* Wo = (const float*)d_in[8];
    const float* bo = (const float*)d_in[9];

    u16* ws = (u16*)d_ws;
    const size_t MB1 = 1024 * 1024;

    // Fixed: 4 transposed weights (4M elems) + qb16 (8M) + Qp (8M).
    u16* WqT = ws;
    u16* WkT = ws + MB1;
    u16* WvT = ws + 2 * MB1;
    u16* WoT = ws + 3 * MB1;
    u16* qb16 = ws + 4 * MB1;
    u16* Qp   = qb16 + (size_t)MQ * 1024;                  // attn O aliases
    u16* kvb  = Qp + (size_t)MQ * 1024;

    // Adaptive KV slicing (rows multiple of 1024): kvb, Kp, Vt
    size_t ws_elems = ws_size / 2;
    size_t fixed = 4 * MB1 + 2 * (size_t)MQ * 1024;        // 20M elems
    size_t avail = (ws_elems > fixed) ? (ws_elems - fixed) : 0;
    long long max_rows = (long long)(avail / (3 * 1024));
    int slice_rows = (int)((max_rows / 1024) * 1024);
    if (slice_rows >= MKV) slice_rows = MKV;
    else if (slice_rows >= 16384) slice_rows = 16384;      // even 2-slice split
    if (slice_rows < 1024) slice_rows = 1024;

    u16* Kp = kvb + (size_t)slice_rows * 1024;
    u16* Vt = Kp + (size_t)slice_rows * 1024;

    dim3 tb(256);
    transpose_w_cvt4<<<dim3(16, 16, 4), tb, 0, stream>>>(Wq, Wk, Wv, Wo, WqT, WkT, WvT, WoT);
    cvt_f32_bf16<<<dim3(MQ * 1024 / (256 * 8)), tb, 0, stream>>>(query, qb16);

    int qdone = 0;                                         // Q 128-row tiles completed
    for (int r0 = 0; r0 < MKV; r0 += slice_rows) {
        int rows = MKV - r0;
        if (rows > slice_rows) rows = slice_rows;
        cvt_f32_bf16<<<dim3(rows * 1024 / (256 * 8)), tb, 0, stream>>>(
            keyin + (size_t)r0 * 1024, kvb);
        int nmKV = rows / 128;
        int nmQ = rows / 512;                              // Q rows = kv rows / 4, tiles of 128
        proj_fused<<<dim3((2 * nmKV + nmQ) * 4), dim3(512), 0, stream>>>(
            kvb, qb16 + (size_t)qdone * 128 * 1024,
            WkT, WvT, WqT, bk, bv, bq,
            Kp, Vt, Qp + (size_t)qdone * 128 * 1024, nmKV, nmQ);
        size_t qoff = (size_t)(r0 / 4) * 1024;
        attn_kernel<<<dim3((rows / 256) * 16), tb, 0, stream>>>(
            Qp + qoff, Kp, Vt, Qp + qoff);
        qdone += nmQ;
    }

    gemm_bias<2><<<dim3(MQ / 128, 8), tb, 0, stream>>>(Qp, WoT, bo, d_out);
}

// Round 14
// 310.716 us; speedup vs baseline: 1.0656x; 1.0656x over previous
//
#include <hip/hip_runtime.h>
#include <hip/hip_bf16.h>
#include <stdint.h>

// Problem constants
#define DMODEL 1024
#define NHEADS 16
#define DK 64
#define TQ 64      // chunk_len
#define LKV 256    // kv length per chunk (NN*NL)
#define MQ 8192    // B*S = query rows
#define MKV 32768  // B*NC*L = kv rows

typedef __bf16 bf16x8 __attribute__((ext_vector_type(8)));
typedef float f32x4 __attribute__((ext_vector_type(4)));
typedef unsigned short u16x8 __attribute__((ext_vector_type(8)));
typedef unsigned short u16;

__device__ __forceinline__ unsigned short f2bf(float f) {
    union { float f; unsigned int i; } x; x.f = f;
    unsigned int r = (x.i + 0x7FFFu + ((x.i >> 16) & 1u)) >> 16;
    return (unsigned short)r;
}

__device__ __forceinline__ void gload_lds16(const void* g, void* l) {
    __builtin_amdgcn_global_load_lds(
        (const __attribute__((address_space(1))) unsigned int*)g,
        (__attribute__((address_space(3))) unsigned int*)l, 16, 0, 0);
}

// ---------------- f32 -> bf16 convert (8 elems/thread) ----------------
__global__ __launch_bounds__(256) void cvt_f32_bf16(const float* __restrict__ in,
                                                    unsigned short* __restrict__ out) {
    long long i = ((long long)blockIdx.x * 256 + threadIdx.x) * 8;
    f32x4 a = *(const f32x4*)(in + i);
    f32x4 b = *(const f32x4*)(in + i + 4);
    u16x8 o;
    o[0] = f2bf(a[0]); o[1] = f2bf(a[1]); o[2] = f2bf(a[2]); o[3] = f2bf(a[3]);
    o[4] = f2bf(b[0]); o[5] = f2bf(b[1]); o[6] = f2bf(b[2]); o[7] = f2bf(b[3]);
    *(u16x8*)(out + i) = o;
}

// ---------------- fused weight transpose+convert: Wt[n][k] = bf16(W[k][n]) ----------------
__global__ __launch_bounds__(256) void transpose_w_cvt4(const float* __restrict__ w0,
                                                        const float* __restrict__ w1,
                                                        const float* __restrict__ w2,
                                                        const float* __restrict__ w3,
                                                        u16* __restrict__ o0,
                                                        u16* __restrict__ o1,
                                                        u16* __restrict__ o2,
                                                        u16* __restrict__ o3) {
    __shared__ float tile[64][65];
    const float* in; u16* out;
    switch (blockIdx.z) {
        case 0: in = w0; out = o0; break;
        case 1: in = w1; out = o1; break;
        case 2: in = w2; out = o2; break;
        default: in = w3; out = o3; break;
    }
    int bi = blockIdx.y, bj = blockIdx.x;
    int tid = threadIdx.x;
    int c = tid & 63, r0 = tid >> 6;
#pragma unroll
    for (int p = 0; p < 16; ++p) {
        int r = r0 + 4 * p;
        tile[r][c] = in[(size_t)(bi * 64 + r) * 1024 + bj * 64 + c];
    }
    __syncthreads();
#pragma unroll
    for (int p = 0; p < 16; ++p) {
        int r = r0 + 4 * p;
        out[(size_t)(bj * 64 + r) * 1024 + bi * 64 + c] = f2bf(tile[c][r]);
    }
}

// ---------------- 128x128 GEMM (proven) for the O projection ----------------
template <int OUTMODE>
__global__ __launch_bounds__(256) void gemm_bias(const u16* __restrict__ A,
                                                 const u16* __restrict__ Bt,
                                                 const float* __restrict__ bias,
                                                 void* __restrict__ OutV) {
    __shared__ alignas(16) u16 aLds[128 * 32];
    __shared__ alignas(16) u16 bLds[128 * 32];

    int tid = threadIdx.x;
    int lane = tid & 63, wid = tid >> 6;
    int m0 = blockIdx.x * 128;
    int n0 = blockIdx.y * 128;
    int wr = (wid >> 1) * 64, wc = (wid & 1) * 64;

    f32x4 zero = {0.f, 0.f, 0.f, 0.f};
    f32x4 acc[4][4];
#pragma unroll
    for (int i = 0; i < 4; ++i)
#pragma unroll
        for (int j = 0; j < 4; ++j) acc[i][j] = zero;

    int sr = lane >> 2;
    int sk = (lane & 3) * 8;
    const u16* aG = A + (size_t)(m0 + sr) * 1024 + sk;
    const u16* bG = Bt + (size_t)(n0 + sr) * 1024 + sk;
    int c0 = wid, c1 = wid + 4;

    int fr = lane & 15, fg = (lane >> 4) * 8;

    for (int kt = 0; kt < 1024; kt += 32) {
        gload_lds16(aG + (size_t)(c0 * 16) * 1024 + kt, aLds + c0 * 512);
        gload_lds16(aG + (size_t)(c1 * 16) * 1024 + kt, aLds + c1 * 512);
        gload_lds16(bG + (size_t)(c0 * 16) * 1024 + kt, bLds + c0 * 512);
        gload_lds16(bG + (size_t)(c1 * 16) * 1024 + kt, bLds + c1 * 512);
        __syncthreads();

        bf16x8 af[4], bf[4];
#pragma unroll
        for (int mt = 0; mt < 4; ++mt)
            af[mt] = *(const bf16x8*)&aLds[(wr + mt * 16 + fr) * 32 + fg];
#pragma unroll
        for (int nt = 0; nt < 4; ++nt)
            bf[nt] = *(const bf16x8*)&bLds[(wc + nt * 16 + fr) * 32 + fg];
#pragma unroll
        for (int mt = 0; mt < 4; ++mt)
#pragma unroll
            for (int nt = 0; nt < 4; ++nt)
                acc[mt][nt] = __builtin_amdgcn_mfma_f32_16x16x32_bf16(af[mt], bf[nt], acc[mt][nt], 0, 0, 0);
        __syncthreads();
    }

    float bv[4];
#pragma unroll
    for (int nt = 0; nt < 4; ++nt) bv[nt] = bias[n0 + wc + nt * 16 + fr];

    if (OUTMODE == 0) {
        u16* Out = (u16*)OutV;
#pragma unroll
        for (int mt = 0; mt < 4; ++mt)
#pragma unroll
            for (int r = 0; r < 4; ++r) {
                size_t row = (size_t)(m0 + wr + mt * 16 + (lane >> 4) * 4 + r);
#pragma unroll
                for (int nt = 0; nt < 4; ++nt)
                    Out[row * 1024 + n0 + wc + nt * 16 + fr] = f2bf(acc[mt][nt][r] + bv[nt]);
            }
    } else {
        float* Out = (float*)OutV;
#pragma unroll
        for (int mt = 0; mt < 4; ++mt)
#pragma unroll
            for (int r = 0; r < 4; ++r) {
                size_t row = (size_t)(m0 + wr + mt * 16 + (lane >> 4) * 4 + r);
#pragma unroll
                for (int nt = 0; nt < 4; ++nt)
                    Out[row * 1024 + n0 + wc + nt * 16 + fr] = acc[mt][nt][r] + bv[nt];
            }
    }
}

// ================= fused Q/K/V projection: counted-vmcnt pipeline (r12) =================
// Triple-buffered B, boundary wait vmcnt(4) (never 0 until t=14).  FULLY UNROLLED
// t-loop: all buffer indices, boundary conds, and ds/stage addresses const-fold
// (kills the ~1500 cyc/tile VALU addr overhead seen at VALUBusy=23%).

__device__ __forceinline__ void stage64(const u16* src, u16* ldsTile, int row0, int tid) {
    int w = tid >> 6, l = tid & 63;
    int r = row0 + w * 8 + (l >> 3);
    int k16 = (l & 7) ^ ((l >> 3) & 7);
    gload_lds16(src + (size_t)r * 1024 + k16 * 8, ldsTile + (size_t)(row0 + w * 8) * 64);
}

#define SBAR() do { __builtin_amdgcn_s_barrier(); asm volatile("" ::: "memory"); } while (0)

__global__ __launch_bounds__(512, 2) void proj_fused(const u16* __restrict__ Akv,
                                                     const u16* __restrict__ Aq,
                                                     const u16* __restrict__ WkT,
                                                     const u16* __restrict__ WvT,
                                                     const u16* __restrict__ WqT,
                                                     const float* __restrict__ bk,
                                                     const float* __restrict__ bv,
                                                     const float* __restrict__ bq,
                                                     u16* __restrict__ Kp,
                                                     u16* __restrict__ Vt,
                                                     u16* __restrict__ Qp,
                                                     int nmKV, int nmQ) {
    __shared__ alignas(16) u16 lds[81920];   // 160 KB: A0,A1,B0,B1,B2
    u16* ldsA0 = lds;
    u16* ldsA1 = lds + 16384;
    u16* ldsB  = lds + 32768;                // 3 x 16384

    int tid = threadIdx.x, lane = tid & 63, wid = tid >> 6;
    int wm = wid >> 2, wn = wid & 3;

    // bijective XCD swizzle over the whole grid
    int nB = gridDim.x;
    int bid = blockIdx.x;
    int qq = nB >> 3, rr = nB & 7;
    int xcd = bid & 7, idx = bid >> 3;
    int wg = (xcd < rr) ? xcd * (qq + 1) + idx : rr * (qq + 1) + (xcd - rr) * qq + idx;

    // decode role
    const u16* A; const u16* B; const float* bias; u16* Out; int mode;
    int nKV4 = nmKV * 4;
    int lwg;
    if (wg < nKV4)            { lwg = wg;            A = Akv; B = WkT; bias = bk; Out = Kp; mode = 0; }
    else if (wg < 2 * nKV4)   { lwg = wg - nKV4;     A = Akv; B = WvT; bias = bv; Out = Vt; mode = 1; }
    else                      { lwg = wg - 2 * nKV4; A = Aq;  B = WqT; bias = bq; Out = Qp; mode = 0; }
    int m0 = (lwg >> 2) * 256;
    int n0 = (lwg & 3) * 256;

    const u16* aSrc = A + (size_t)m0 * 1024;
    const u16* bSrc = B + (size_t)n0 * 1024;

    f32x4 zero = {0.f, 0.f, 0.f, 0.f};
    f32x4 acc[8][4];
#pragma unroll
    for (int i = 0; i < 8; ++i)
#pragma unroll
        for (int j = 0; j < 4; ++j) acc[i][j] = zero;

    bf16x8 aR[4][2], b0R[2][2], b1R[2][2];

#define READ_A(lA, half)                                                         \
    do {                                                                         \
        _Pragma("unroll") for (int mf = 0; mf < 4; ++mf) {                       \
            int row = wm * 128 + (half) * 64 + mf * 16 + (lane & 15);            \
            _Pragma("unroll") for (int kk = 0; kk < 2; ++kk) {                   \
                int k16 = kk * 4 + (lane >> 4);                                  \
                aR[mf][kk] = *(const bf16x8*)&(lA)[row * 64 + ((k16 ^ (row & 7)) << 3)]; \
            }                                                                    \
        }                                                                        \
    } while (0)
#define READ_B(lB, half, dst)                                                    \
    do {                                                                         \
        _Pragma("unroll") for (int nf = 0; nf < 2; ++nf) {                       \
            int row = wn * 64 + (half) * 32 + nf * 16 + (lane & 15);             \
            _Pragma("unroll") for (int kk = 0; kk < 2; ++kk) {                   \
                int k16 = kk * 4 + (lane >> 4);                                  \
                dst[nf][kk] = *(const bf16x8*)&(lB)[row * 64 + ((k16 ^ (row & 7)) << 3)]; \
            }                                                                    \
        }                                                                        \
    } while (0)
#define MFMA16(mh, nh, bR)                                                       \
    do {                                                                         \
        __builtin_amdgcn_s_setprio(1);                                           \
        _Pragma("unroll") for (int mf = 0; mf < 4; ++mf)                         \
            _Pragma("unroll") for (int nf = 0; nf < 2; ++nf)                     \
                _Pragma("unroll") for (int kk = 0; kk < 2; ++kk)                 \
                    acc[(mh)*4 + mf][(nh)*2 + nf] =                              \
                        __builtin_amdgcn_mfma_f32_16x16x32_bf16(                 \
                            aR[mf][kk], bR[nf][kk], acc[(mh)*4 + mf][(nh)*2 + nf], 0, 0, 0); \
        __builtin_amdgcn_s_setprio(0);                                           \
    } while (0)

    // ---- prologue: B(0)->Bbuf0, A(0)->A0, B(1)->Bbuf1; certify B(0),A(0) ----
    stage64(bSrc, ldsB, 0, tid);          stage64(bSrc, ldsB, 64, tid);
    stage64(bSrc, ldsB, 128, tid);        stage64(bSrc, ldsB, 192, tid);
    stage64(aSrc, ldsA0, 0, tid);         stage64(aSrc, ldsA0, 64, tid);
    stage64(aSrc, ldsA0, 128, tid);       stage64(aSrc, ldsA0, 192, tid);
    stage64(bSrc + 64, ldsB + 16384, 0, tid);   stage64(bSrc + 64, ldsB + 16384, 64, tid);
    stage64(bSrc + 64, ldsB + 16384, 128, tid); stage64(bSrc + 64, ldsB + 16384, 192, tid);
    asm volatile("s_waitcnt vmcnt(4)" ::: "memory");   // B(1)'s 4 stay in flight
    SBAR();

#pragma unroll
    for (int t = 0; t < 16; ++t) {
        int bi = t % 3;                                // const-folds under full unroll
        u16* lA = (t & 1) ? ldsA1 : ldsA0;
        u16* lB = ldsB + bi * 16384;
        u16* pA = (t & 1) ? ldsA0 : ldsA1;             // A(t+1) dest
        int bi2 = (t + 2) % 3;                         // B(t+2) dest index
        u16* pB = ldsB + bi2 * 16384;
        const u16* aN = aSrc + (t + 1) * 64;
        const u16* bN2 = bSrc + (t + 2) * 64;
        bool pfA = (t < 15), pfB = (t < 14);

        // q0: read A0,B0; stage A(t+1) rows 0,128; mfma (0,0)
        READ_A(lA, 0);
        READ_B(lB, 0, b0R);
        if (pfA) { stage64(aN, pA, 0, tid); stage64(aN, pA, 128, tid); }
        MFMA16(0, 0, b0R);

        // q1: read B1; stage A(t+1) rows 64,192; mfma (0,1)
        READ_B(lB, 1, b1R);
        if (pfA) { stage64(aN, pA, 64, tid); stage64(aN, pA, 192, tid); }
        MFMA16(0, 1, b1R);

        // q2: read A1; stage B(t+2) rows 0,64; mfma (1,1)
        READ_A(lA, 1);
        if (pfB) { stage64(bN2, pB, 0, tid); stage64(bN2, pB, 64, tid); }
        MFMA16(1, 1, b1R);

        // q3: stage B(t+2) rows 128,192; mfma (1,0)
        if (pfB) { stage64(bN2, pB, 128, tid); stage64(bN2, pB, 192, tid); }
        MFMA16(1, 0, b0R);

        // boundary: counted wait — certify A(t+1)+B(t+1), keep B(t+2) in flight
        if (t < 14)      { asm volatile("s_waitcnt vmcnt(4)" ::: "memory"); SBAR(); }
        else if (t == 14){ asm volatile("s_waitcnt vmcnt(0)" ::: "memory"); SBAR(); }
    }

    // ---- epilogue ----
    float bvv[4];
#pragma unroll
    for (int NF = 0; NF < 4; ++NF) bvv[NF] = bias[n0 + wn * 64 + NF * 16 + (lane & 15)];

    if (mode == 0) {
#pragma unroll
        for (int MF = 0; MF < 8; ++MF)
#pragma unroll
            for (int r = 0; r < 4; ++r) {
                size_t row = (size_t)(m0 + wm * 128 + MF * 16 + (lane >> 4) * 4 + r);
#pragma unroll
                for (int NF = 0; NF < 4; ++NF)
                    Out[row * 1024 + n0 + wn * 64 + NF * 16 + (lane & 15)] =
                        f2bf(acc[MF][NF][r] + bvv[NF]);
            }
    } else {
        // Vt[((bcL*16 + h)*64 + d) * 256 + lv]
#pragma unroll
        for (int MF = 0; MF < 8; ++MF)
#pragma unroll
            for (int r = 0; r < 4; ++r) {
                int gm = m0 + wm * 128 + MF * 16 + (lane >> 4) * 4 + r;
                int bc2 = gm >> 8, lv = gm & 255;
#pragma unroll
                for (int NF = 0; NF < 4; ++NF) {
                    int n = n0 + wn * 64 + NF * 16 + (lane & 15);
                    int hh = n >> 6, dd = n & 63;
                    Out[(size_t)((bc2 * 16 + hh) * 64 + dd) * 256 + lv] =
                        f2bf(acc[MF][NF][r] + bvv[NF]);
                }
            }
    }
#undef READ_A
#undef READ_B
#undef MFMA16
}

// ---------------- attention: per (bcLocal, h) block ----------------
// Chunked XCD swizzle: all 16 head-blocks of one bc land on the same XCD
// so K[bc]/V[bc] are fetched into that XCD's L2 once, not 8x.
__global__ __launch_bounds__(256) void attn_kernel(const u16* __restrict__ Q,
                                                   const u16* __restrict__ K,
                                                   const u16* __restrict__ Vt,
                                                   u16* O) {
    __shared__ alignas(16) u16 pLds[64 * 264];

    int tid = threadIdx.x;
    int lane = tid & 63, w = tid >> 6;
    int nBl = gridDim.x;
    int wk = (blockIdx.x & 7) * (nBl >> 3) + (blockIdx.x >> 3);  // chunked (nBl%8==0)
    int bc = wk >> 4, h = wk & 15;
    int fr = lane & 15, g = lane >> 4;

    const u16* qb = Q + (size_t)(bc * 64 + w * 16 + fr) * 1024 + h * 64 + g * 8;
    bf16x8 qf0 = *(const bf16x8*)qb;
    bf16x8 qf1 = *(const bf16x8*)(qb + 32);

    const u16* kb = K + (size_t)(bc * 256 + fr) * 1024 + h * 64 + g * 8;

    f32x4 zero = {0.f, 0.f, 0.f, 0.f};
    f32x4 sc[16];
#pragma unroll
    for (int nt = 0; nt < 16; ++nt) sc[nt] = zero;

#pragma unroll
    for (int nt = 0; nt < 16; ++nt) {
        bf16x8 kf0 = *(const bf16x8*)(kb + (size_t)(nt * 16) * 1024);
        bf16x8 kf1 = *(const bf16x8*)(kb + (size_t)(nt * 16) * 1024 + 32);
        sc[nt] = __builtin_amdgcn_mfma_f32_16x16x32_bf16(qf0, kf0, sc[nt], 0, 0, 0);
        sc[nt] = __builtin_amdgcn_mfma_f32_16x16x32_bf16(qf1, kf1, sc[nt], 0, 0, 0);
    }

    const float scale = 0.125f;
    float mx[4], sum[4];
#pragma unroll
    for (int r = 0; r < 4; ++r) {
        float m = -1e30f;
#pragma unroll
        for (int nt = 0; nt < 16; ++nt) {
            sc[nt][r] *= scale;
            m = fmaxf(m, sc[nt][r]);
        }
#pragma unroll
        for (int x = 1; x < 16; x <<= 1) m = fmaxf(m, __shfl_xor(m, x, 64));
        mx[r] = m;
        sum[r] = 0.f;
    }
#pragma unroll
    for (int nt = 0; nt < 16; ++nt)
#pragma unroll
        for (int r = 0; r < 4; ++r) {
            float p = __expf(sc[nt][r] - mx[r]);
            sum[r] += p;
            pLds[(w * 16 + g * 4 + r) * 264 + nt * 16 + fr] = f2bf(p);
        }
#pragma unroll
    for (int r = 0; r < 4; ++r)
#pragma unroll
        for (int x = 1; x < 16; x <<= 1) sum[r] += __shfl_xor(sum[r], x, 64);

    __syncthreads();

    f32x4 oa[4];
#pragma unroll
    for (int nt = 0; nt < 4; ++nt) oa[nt] = zero;

    const u16* vtb = Vt + (size_t)((bc * 16 + h) * 64) * 256;
#pragma unroll
    for (int ks = 0; ks < 8; ++ks) {
        bf16x8 pf = *(const bf16x8*)&pLds[(w * 16 + fr) * 264 + ks * 32 + g * 8];
#pragma unroll
        for (int nt = 0; nt < 4; ++nt) {
            bf16x8 vf = *(const bf16x8*)(vtb + (size_t)(nt * 16 + fr) * 256 + ks * 32 + g * 8);
            oa[nt] = __builtin_amdgcn_mfma_f32_16x16x32_bf16(pf, vf, oa[nt], 0, 0, 0);
        }
    }

    float rs[4];
#pragma unroll
    for (int r = 0; r < 4; ++r) rs[r] = 1.0f / sum[r];

    u16* ob = O + (size_t)(bc * 64 + w * 16 + g * 4) * 1024 + h * 64 + fr;
#pragma unroll
    for (int nt = 0; nt < 4; ++nt)
#pragma unroll
        for (int r = 0; r < 4; ++r)
            ob[(size_t)r * 1024 + nt * 16] = f2bf(oa[nt][r] * rs[r]);
}

extern "C" void kernel_launch(void* const* d_in, const int* in_sizes, int n_in,
                              void* d_out, int out_size, void* d_ws, size_t ws_size,
                              hipStream_t stream) {
    const float* query = (const float*)d_in[0];
    const float* keyin = (const float*)d_in[1];
    const float* Wq = (const float*)d_in[2];
    const float* bq = (const float*)d_in[3];
    const float* Wk = (const float*)d_in[4];
    const float* bk = (const float*)d_in[5];
    const float* Wv = (const float*)d_in[6];
    const float* bv = (const float*)d_in[7];
    const float* Wo = (const float*)d_in[8];
    const float* bo = (const float*)d_in[9];

    u16* ws = (u16*)d_ws;
    const size_t MB1 = 1024 * 1024;

    // Fixed: 4 transposed weights (4M elems) + qb16 (8M) + Qp (8M).
    u16* WqT = ws;
    u16* WkT = ws + MB1;
    u16* WvT = ws + 2 * MB1;
    u16* WoT = ws + 3 * MB1;
    u16* qb16 = ws + 4 * MB1;
    u16* Qp   = qb16 + (size_t)MQ * 1024;                  // attn O aliases
    u16* kvb  = Qp + (size_t)MQ * 1024;

    // Adaptive KV slicing (rows multiple of 1024): kvb, Kp, Vt
    size_t ws_elems = ws_size / 2;
    size_t fixed = 4 * MB1 + 2 * (size_t)MQ * 1024;        // 20M elems
    size_t avail = (ws_elems > fixed) ? (ws_elems - fixed) : 0;
    long long max_rows = (long long)(avail / (3 * 1024));
    int slice_rows = (int)((max_rows / 1024) * 1024);
    if (slice_rows >= MKV) slice_rows = MKV;
    else if (slice_rows >= 16384) slice_rows = 16384;      // even 2-slice split
    if (slice_rows < 1024) slice_rows = 1024;

    u16* Kp = kvb + (size_t)slice_rows * 1024;
    u16* Vt = Kp + (size_t)slice_rows * 1024;

    dim3 tb(256);
    transpose_w_cvt4<<<dim3(16, 16, 4), tb, 0, stream>>>(Wq, Wk, Wv, Wo, WqT, WkT, WvT, WoT);
    cvt_f32_bf16<<<dim3(MQ * 1024 / (256 * 8)), tb, 0, stream>>>(query, qb16);

    int qdone = 0;                                         // Q m-tiles completed
    for (int r0 = 0; r0 < MKV; r0 += slice_rows) {
        int rows = MKV - r0;
        if (rows > slice_rows) rows = slice_rows;
        cvt_f32_bf16<<<dim3(rows * 1024 / (256 * 8)), tb, 0, stream>>>(
            keyin + (size_t)r0 * 1024, kvb);
        int nmKV = rows / 256;
        int nmQ = rows / 1024;                             // Q tiles matching this KV range
        proj_fused<<<dim3(nmKV * 8 + nmQ * 4), dim3(512), 0, stream>>>(
            kvb, qb16 + (size_t)qdone * 256 * 1024,
            WkT, WvT, WqT, bk, bv, bq,
            Kp, Vt, Qp + (size_t)qdone * 256 * 1024, nmKV, nmQ);
        size_t qoff = (size_t)(r0 / 4) * 1024;
        attn_kernel<<<dim3((rows / 256) * 16), tb, 0, stream>>>(
            Qp + qoff, Kp, Vt, Qp + qoff);
        qdone += nmQ;
    }

    gemm_bias<2><<<dim3(MQ / 128, 8), tb, 0, stream>>>(Qp, WoT, bo, d_out);
}